// Round 8
// baseline (247.436 us; speedup 1.0000x reference)
//
#include <hip/hip_runtime.h>
#include <math.h>

// FitzHugh-Nagumo RK4, one thread per trajectory, 2047 sequential steps.
//
// HW model (r1-r7 fits): one wave per SIMD; scalar wave64 f32 op = 2 cy
// execute, dep latency ~4 cy; v_pk_fma = 4 cy execute (no throughput win,
// longer chain stalls -> r7 regression). Scalar floor = 36 ops x 2 cy =
// 72 cy/step. R5 measured 140 cy VALU-execute/step => ~70 emitted VALU
// instrs (~2x my op count): compiler rematerialized constants each iter
// (VGPR_Count=20). Fix: whole step body in inline asm, constants pinned
// in SGPRs (each VALU op uses <=1 const), temps hand-allocated, schedule
// with all dep distances >=2 instructions.
//
// Formulas identical to round 5 (passed, absmax 0.015625):
//   y2 = fma(B1,x,fma(A1,y,C1));  y3,y4 incremental (f_y linear, folded)
//   x-stages: x_s = fma(mhcc3,q,fma(hc,s,x)) etc.
//   xn = -x/3 + x2/3 + 2/3 x3 + E4x*x4 + d6c*y4 - d6cc3*q4
//   yn = -y/3 + y2/3 + 2/3 y3 + E4y*y4 + d6nic*x4 + d6anc

__global__ __launch_bounds__(64) void fhn_rk4_kernel(
    const float* __restrict__ x0, const float* __restrict__ y0,
    const float* __restrict__ pa, const float* __restrict__ pb,
    const float* __restrict__ pc, float2* __restrict__ out,
    int B, int num_steps)
{
    const int i = blockIdx.x * 64 + threadIdx.x;
    if (i >= B) return;

    const float a = pa[0];
    const float b = pb[0];
    const float c = pc[0];

    const float dt  = 0.1f;
    const float h   = 0.05f;
    const float dt6 = 0.1f / 6.0f;
    const float c3  = 1.0f / 3.0f;

    // x-side constants
    const float hc     = h * c;
    const float mhcc3  = -(h * c * c3);
    const float dc     = dt * c;
    const float mdcc3  = -(dt * c * c3);
    const float d6c    = dt6 * c;
    const float md6cc3 = -(dt6 * c * c3);
    const float E4x    = c3 + d6c;

    // y-side constants
    const float nic   = -1.0f / c;
    const float nicb  = -b / c;
    const float anc   = a / c;
    const float A1    = 1.0f + h * nicb;
    const float B1    = h * nic;
    const float C1    = h * anc;
    const float hnicb = h * nicb;
    const float dnic  = dt * nic;
    const float dnicb = dt * nicb;
    const float danc  = dt * anc;
    const float d6nic = dt6 * nic;
    const float d6anc = dt6 * anc;
    const float E4y   = c3 + dt6 * nicb;

    const float mc3 = -c3;
    const float c23 = 2.0f * c3;

    float x = x0[i];
    float y = y0[i];

    float2* o = out + i;
    *o = make_float2(x, y);
    o += B;

#pragma unroll 2
    for (int s = 1; s < num_steps; ++s, o += B) {
        float p, q, sv, tx, iv, vx, wy;
        float x2, x3, x4, y2, y3, y4, yha, yda;
        asm(
            // schedule: all dependent pairs >= 2 instructions apart
            "v_mul_f32 %[p], %[x], %[x]\n\t"             // 1  p1 = x*x
            "v_fma_f32 %[iv], %[sA1], %[y], %[vC1]\n\t"  // 2  i1 = A1*y+C1
            "v_add_f32 %[sv], %[x], %[y]\n\t"            // 3  s1 = x+y
            "v_mul_f32 %[q], %[p], %[x]\n\t"             // 4  q1 = p1*x
            "v_fma_f32 %[y2], %[sB1], %[x], %[iv]\n\t"   // 5  y2
            "v_fma_f32 %[tx], %[shc], %[sv], %[x]\n\t"   // 6  tx1
            "v_add_f32 %[yha], %[y], %[vC1]\n\t"         // 7  yha = y+C1
            "v_fma_f32 %[x2], %[smhcc3], %[q], %[tx]\n\t"// 8  x2
            "v_fma_f32 %[iv], %[shnicb], %[y2], %[yha]\n\t" // 9 i2
            "v_add_f32 %[yda], %[y], %[vdanc]\n\t"       // 10 yda
            "v_mul_f32 %[p], %[x2], %[x2]\n\t"           // 11 p2
            "v_add_f32 %[sv], %[x2], %[y2]\n\t"          // 12 s2
            "v_fma_f32 %[y3], %[sB1], %[x2], %[iv]\n\t"  // 13 y3
            "v_mul_f32 %[q], %[p], %[x2]\n\t"            // 14 q2
            "v_fma_f32 %[tx], %[shc], %[sv], %[x]\n\t"   // 15 tx2
            "v_mul_f32 %[vx], %[smc3], %[x]\n\t"         // 16 vx = -x/3
            "v_fma_f32 %[x3], %[smhcc3], %[q], %[tx]\n\t"// 17 x3
            "v_fma_f32 %[wy], %[smc3], %[y], %[vd6anc]\n\t" // 18 wy
            "v_fma_f32 %[vx], %[sc3], %[x2], %[vx]\n\t"  // 19 vx += x2/3
            "v_mul_f32 %[p], %[x3], %[x3]\n\t"           // 20 p3
            "v_add_f32 %[sv], %[x3], %[y3]\n\t"          // 21 s3
            "v_fma_f32 %[iv], %[sdnicb], %[y3], %[yda]\n\t" // 22 i3
            "v_mul_f32 %[q], %[p], %[x3]\n\t"            // 23 q3
            "v_fma_f32 %[tx], %[sdc], %[sv], %[x]\n\t"   // 24 tx3
            "v_fma_f32 %[y4], %[sdnic], %[x3], %[iv]\n\t"// 25 y4
            "v_fma_f32 %[wy], %[sc3], %[y2], %[wy]\n\t"  // 26 wy += y2/3
            "v_fma_f32 %[x4], %[smdcc3], %[q], %[tx]\n\t"// 27 x4
            "v_fma_f32 %[vx], %[sc23], %[x3], %[vx]\n\t" // 28 vx += 2/3 x3
            "v_fma_f32 %[wy], %[sc23], %[y3], %[wy]\n\t" // 29 wy += 2/3 y3
            "v_mul_f32 %[p], %[x4], %[x4]\n\t"           // 30 p4
            "v_fma_f32 %[vx], %[sE4x], %[x4], %[vx]\n\t" // 31 vx += E4x*x4
            "v_fma_f32 %[wy], %[sE4y], %[y4], %[wy]\n\t" // 32 wy += E4y*y4
            "v_mul_f32 %[q], %[p], %[x4]\n\t"            // 33 q4
            "v_fma_f32 %[vx], %[sd6c], %[y4], %[vx]\n\t" // 34 vx += d6c*y4
            "v_fma_f32 %[y], %[sd6nic], %[x4], %[wy]\n\t"// 35 yn
            "v_fma_f32 %[x], %[smd6cc3], %[q], %[vx]\n\t"// 36 xn
            : [x] "+v"(x), [y] "+v"(y),
              [p] "=&v"(p), [q] "=&v"(q), [sv] "=&v"(sv), [tx] "=&v"(tx),
              [iv] "=&v"(iv), [vx] "=&v"(vx), [wy] "=&v"(wy),
              [x2] "=&v"(x2), [x3] "=&v"(x3), [x4] "=&v"(x4),
              [y2] "=&v"(y2), [y3] "=&v"(y3), [y4] "=&v"(y4),
              [yha] "=&v"(yha), [yda] "=&v"(yda)
            : [sA1] "s"(A1), [sB1] "s"(B1), [shc] "s"(hc),
              [smhcc3] "s"(mhcc3), [shnicb] "s"(hnicb), [sdnic] "s"(dnic),
              [sdnicb] "s"(dnicb), [sdc] "s"(dc), [smdcc3] "s"(mdcc3),
              [smc3] "s"(mc3), [sc3] "s"(c3), [sc23] "s"(c23),
              [sE4x] "s"(E4x), [sE4y] "s"(E4y), [sd6c] "s"(d6c),
              [smd6cc3] "s"(md6cc3), [sd6nic] "s"(d6nic),
              [vC1] "v"(C1), [vdanc] "v"(danc), [vd6anc] "v"(d6anc));

        *o = make_float2(x, y);
    }
}

extern "C" void kernel_launch(void* const* d_in, const int* in_sizes, int n_in,
                              void* d_out, int out_size, void* d_ws, size_t ws_size,
                              hipStream_t stream) {
    const float* x0 = (const float*)d_in[0];
    const float* y0 = (const float*)d_in[1];
    const float* pa = (const float*)d_in[2];
    const float* pb = (const float*)d_in[3];
    const float* pc = (const float*)d_in[4];
    const int B = in_sizes[0];
    const int num_steps = out_size / (2 * B);

    float2* out = (float2*)d_out;

    const int block = 64;
    const int grid = (B + block - 1) / block;
    fhn_rk4_kernel<<<grid, block, 0, stream>>>(x0, y0, pa, pb, pc, out, B, num_steps);
}